// Round 7
// baseline (790.162 us; speedup 1.0000x reference)
//
#include <hip/hip_runtime.h>

#define D 4096

typedef float fx4 __attribute__((ext_vector_type(4)));

// ws layout (floats), total 4D+4:
//   CNT = 0           block-completion counter (uint; memset to 0 each call)
//   CS0 = 4           colsum0 [D]   (atomics; memset first)
//   CS1 = D+4         colsum1 [D]   (atomics; memset first)
//   RS1 = 2D+4        rowsum1 [D]
//   RS2 = 3D+4        rowsum2 [D]
//   MSG = 0           m0,m1,m2,m3 [4][D] — written at END of messages phase,
//                     overwriting CNT/CS0/CS1/RS* (all dead by then; re-init next call)
#define CNT 0
#define CS0 4
#define CS1 (D + 4)
#define RS1 (2 * D + 4)
#define RS2 (3 * D + 4)
#define MSG 0

// ---------------- fused reduce + messages (last-block-done) ----------------
// 1280 blocks x 1024 threads:
//   [0,128)     t0 colsum: 32-row stripe, thread owns fx4-column tid; atomics CS0
//   [128,256)   t1 colsum: same -> CS1
//   [256,768)   t1 rowsum: 8 rows/block, 2 waves per row -> RS1
//   [768,1280)  t2 rowsum: same -> RS2
// Last block to finish runs the message chain (R3-proven body).
__global__ void __launch_bounds__(1024) reduce_msgs_kernel(
        const float* __restrict__ t0, const float* __restrict__ t1,
        const float* __restrict__ t2, float* __restrict__ ws,
        const int* __restrict__ op0, const int* __restrict__ op1,
        const int* __restrict__ op2, const int* __restrict__ op3) {
    __shared__ float sm[4 * D];      // messages m0..m3 (last block only)
    __shared__ float red[16];        // wave scratch (rowsum combine / block sums)
    __shared__ unsigned int lastflag;
    int b = blockIdx.x;
    int tid = threadIdx.x;

    if (b < 256) {
        // ---- colsum: 32 rows x full 4096 width ----
        const float* A = (b < 128) ? t0 : t1;
        float* out = ws + ((b < 128) ? CS0 : CS1);
        int r0 = (b & 127) * 32;
        const fx4* A4 = (const fx4*)A;
        fx4 acc = (fx4){0.f, 0.f, 0.f, 0.f};
        #pragma unroll 8
        for (int r = 0; r < 32; ++r)
            acc += A4[(size_t)(r0 + r) * (D / 4) + tid];
        atomicAdd(&out[tid * 4 + 0], acc.x);
        atomicAdd(&out[tid * 4 + 1], acc.y);
        atomicAdd(&out[tid * 4 + 2], acc.z);
        atomicAdd(&out[tid * 4 + 3], acc.w);
    } else {
        // ---- rowsum: 8 rows/block, 2 waves (128 lanes) per row ----
        int lb = b - 256;                       // 0..1023
        const float* A = (lb < 512) ? t1 : t2;
        float* out = ws + ((lb < 512) ? RS1 : RS2);
        int s = lb & 511;                       // 8-row stripe
        int wv = tid >> 6, lane = tid & 63;
        int row = s * 8 + (wv >> 1);
        const fx4* R = (const fx4*)(A + (size_t)row * D) + (wv & 1) * 512;
        float p = 0.f;
        #pragma unroll
        for (int j = 0; j < 8; ++j) {
            fx4 v = R[lane + 64 * j];
            p += (v.x + v.y) + (v.z + v.w);
        }
        #pragma unroll
        for (int o = 32; o > 0; o >>= 1) p += __shfl_down(p, o);
        if (lane == 0) red[wv] = p;
        __syncthreads();
        if (tid < 8) out[s * 8 + tid] = red[2 * tid] + red[2 * tid + 1];
    }

    // ---- completion protocol (rocPRIM-style last-block-done) ----
    __threadfence();                            // release: stores/atomics device-visible
    __syncthreads();
    if (tid == 0)
        lastflag = (atomicAdd((unsigned int*)(ws + CNT), 1u) == gridDim.x - 1);
    __syncthreads();
    if (!lastflag) return;
    __threadfence();                            // acquire: see all blocks' stores

    // ================= messages phase (last block, 1024 threads) =================
    float* m0 = sm;
    float* m1 = sm + D;
    float* m2 = sm + 2 * D;
    float* m3 = sm + 3 * D;

    int s0[4], d0[4], s1[4], d1[4], s2[4], d2[4], s3[4], d3[4];
    #pragma unroll
    for (int k = 0; k < 4; ++k) {
        int i = tid + k * 1024;
        s0[k] = op0[i]; d0[k] = op0[D + i];
        s1[k] = op1[i]; d1[k] = op1[D + i];
        s2[k] = op2[i]; d2[k] = op2[D + i];
        s3[k] = op3[i]; d3[k] = op3[D + i];
    }
    float g0[4], g1[4], g2[4], g3[4];
    #pragma unroll
    for (int k = 0; k < 4; ++k) {
        g0[k] = ws[CS0 + s0[k]];
        g1[k] = ws[CS1 + s1[k]];
        g2[k] = ws[RS2 + s2[k]];
        g3[k] = ws[RS1 + s3[k]];
    }

    #pragma unroll
    for (int k = 0; k < 4; ++k) {
        int i = tid + k * 1024;
        m0[i] = 0.f; m1[i] = 0.f; m2[i] = 0.f; m3[i] = 0.f;
    }
    __syncthreads();

    // m0 = remap(colsum0, op0)
    #pragma unroll
    for (int k = 0; k < 4; ++k) atomicAdd(&m0[d0[k]], g0[k]);
    __syncthreads();

    // S0 = sum(m0)
    float p = 0.f;
    #pragma unroll
    for (int k = 0; k < 4; ++k) p += m0[tid + k * 1024];
    #pragma unroll
    for (int o = 32; o > 0; o >>= 1) p += __shfl_down(p, o);
    if ((tid & 63) == 0) red[tid >> 6] = p;
    __syncthreads();
    if (tid == 0) {
        float t = 0.f;
        #pragma unroll
        for (int w = 0; w < 16; ++w) t += red[w];
        red[0] = t;
    }
    __syncthreads();
    float S0 = red[0];
    __syncthreads();

    // m1 = remap(colsum1 + S0, op1)
    #pragma unroll
    for (int k = 0; k < 4; ++k) atomicAdd(&m1[d1[k]], g1[k] + S0);
    __syncthreads();

    // m2 = remap(rowsum2 + 4095*m1, op2)
    #pragma unroll
    for (int k = 0; k < 4; ++k)
        atomicAdd(&m2[d2[k]], g2[k] + 4095.0f * m1[s2[k]]);
    __syncthreads();

    // S2 = sum(m2)
    p = 0.f;
    #pragma unroll
    for (int k = 0; k < 4; ++k) p += m2[tid + k * 1024];
    #pragma unroll
    for (int o = 32; o > 0; o >>= 1) p += __shfl_down(p, o);
    if ((tid & 63) == 0) red[tid >> 6] = p;
    __syncthreads();
    if (tid == 0) {
        float t = 0.f;
        #pragma unroll
        for (int w = 0; w < 16; ++w) t += red[w];
        red[0] = t;
    }
    __syncthreads();
    float S2 = red[0];
    __syncthreads();

    // m3 = remap(rowsum1 + 4095*m0 + S2, op3)
    #pragma unroll
    for (int k = 0; k < 4; ++k)
        atomicAdd(&m3[d3[k]], g3[k] + 4095.0f * m0[s3[k]] + S2);
    __syncthreads();

    // export m0..m3 -> ws[MSG..MSG+4D) (overwrites dead CNT/CS/RS regions)
    {
        fx4* dst = (fx4*)(ws + MSG);
        const fx4* srcm = (const fx4*)sm;
        dst[tid]                = srcm[tid];                 // m0
        dst[tid + 1 * (D / 4)]  = srcm[tid + 1 * (D / 4)];   // m1
        dst[tid + 2 * (D / 4)]  = srcm[tid + 2 * (D / 4)];   // m2
        dst[tid + 3 * (D / 4)]  = srcm[tid + 3 * (D / 4)];   // m3
    }
}

// ---------------- apply broadcasts (R3-proven exact form) ----------------
// 3*D blocks x 256; block b: row (b & 4095) of matrix (b >> 12).
__global__ void __launch_bounds__(256) apply_kernel(
        const float* __restrict__ t0, const float* __restrict__ t1,
        const float* __restrict__ t2, const float* __restrict__ msgs,
        float* __restrict__ out) {
    int b = blockIdx.x;
    int mat = b >> 12;
    int row = b & (D - 1);
    const float* m0 = msgs + 0 * D;
    const float* m1 = msgs + 1 * D;
    const float* m2 = msgs + 2 * D;
    const float* m3 = msgs + 3 * D;
    size_t base = (size_t)row * D;
    fx4* dst = (fx4*)(out + (size_t)mat * D * D + base);

    if (mat == 0) {
        const fx4* src = (const fx4*)(t0 + base);
        const fx4* c4 = (const fx4*)m3;
        for (int i = threadIdx.x; i < D / 4; i += 256) {
            fx4 r = __builtin_nontemporal_load(&src[i]) + c4[i];
            __builtin_nontemporal_store(r, &dst[i]);
        }
    } else if (mat == 1) {
        const fx4* src = (const fx4*)(t1 + base);
        const fx4* c4 = (const fx4*)m2;
        float rr = m0[row];
        for (int i = threadIdx.x; i < D / 4; i += 256) {
            fx4 r = __builtin_nontemporal_load(&src[i]) + c4[i] + rr;
            __builtin_nontemporal_store(r, &dst[i]);
        }
    } else {
        const fx4* src = (const fx4*)(t2 + base);
        float rr = m1[row];
        for (int i = threadIdx.x; i < D / 4; i += 256) {
            fx4 r = __builtin_nontemporal_load(&src[i]) + rr;
            __builtin_nontemporal_store(r, &dst[i]);
        }
    }
}

extern "C" void kernel_launch(void* const* d_in, const int* in_sizes, int n_in,
                              void* d_out, int out_size, void* d_ws, size_t ws_size,
                              hipStream_t stream) {
    const float* t0 = (const float*)d_in[0];
    const float* t1 = (const float*)d_in[1];
    const float* t2 = (const float*)d_in[2];
    const int* op0 = (const int*)d_in[3];
    const int* op1 = (const int*)d_in[4];
    const int* op2 = (const int*)d_in[5];
    const int* op3 = (const int*)d_in[6];
    float* out = (float*)d_out;
    float* ws = (float*)d_ws;

    // zero CNT + CS0 + CS1 (one contiguous range)
    hipMemsetAsync(ws, 0, (2 * D + 4) * sizeof(float), stream);

    reduce_msgs_kernel<<<1280, 1024, 0, stream>>>(t0, t1, t2, ws,
                                                  op0, op1, op2, op3);
    apply_kernel<<<3 * D, 256, 0, stream>>>(t0, t1, t2, ws + MSG, out);
}

// Round 8
// 147.115 us; speedup vs baseline: 5.3710x; 5.3710x over previous
//
#include <hip/hip_runtime.h>

#define D 4096

typedef float fx4 __attribute__((ext_vector_type(4)));

// ws layout (floats):
//   CS0 = 0      colsum0 [D]  (atomics; memset first)
//   CS1 = D      colsum1 [D]  (atomics; memset first)
//   RS1 = 2D     rowsum1 [D]
//   RS2 = 3D     rowsum2 [D]
//   MSG = 4D     m0,m1,m2,m3 [4][D]
#define CS0 0
#define CS1 D
#define RS1 (2 * D)
#define RS2 (3 * D)
#define MSG (4 * D)

// ---------------- pass 1: reductions (R3-proven) ----------------
// 2560 blocks x 256:
//   [0,256)     colsum t0 -> atomics CS0   (per-address contention spans 2 XCDs only)
//   [256,512)   colsum t1 -> atomics CS1
//   [512,1536)  rowsum t1 -> RS1           (2nd t1 read; L2/IC-hit)
//   [1536,2560) rowsum t2 -> RS2           (t2 read LAST -> freshest in IC)
__global__ void __launch_bounds__(256) reduce_all_kernel(
        const float* __restrict__ t0, const float* __restrict__ t1,
        const float* __restrict__ t2, float* __restrict__ ws) {
    int b = blockIdx.x;
    if (b < 512) {
        const float* A = (b < 256) ? t0 : t1;
        float* out = ws + ((b < 256) ? CS0 : CS1);
        int lb = b & 255;
        int c4 = (lb & 3) * 256 + threadIdx.x;     // fx4-column 0..1023
        int r0 = (lb >> 2) * 64;                   // 64-row stripe
        const fx4* A4 = (const fx4*)A;
        fx4 s = (fx4){0.f, 0.f, 0.f, 0.f};
        #pragma unroll 8
        for (int r = 0; r < 64; ++r)
            s += A4[(size_t)(r0 + r) * (D / 4) + c4];
        atomicAdd(&out[c4 * 4 + 0], s.x);
        atomicAdd(&out[c4 * 4 + 1], s.y);
        atomicAdd(&out[c4 * 4 + 2], s.z);
        atomicAdd(&out[c4 * 4 + 3], s.w);
    } else {
        int lb = (b - 512) & 1023;                 // 0..1023
        const float* A = (b < 1536) ? t1 : t2;
        float* out = ws + ((b < 1536) ? RS1 : RS2);
        int wid = threadIdx.x >> 6, lane = threadIdx.x & 63;
        int row = lb * 4 + wid;
        const fx4* R = (const fx4*)(A + (size_t)row * D);
        float s = 0.f;
        #pragma unroll
        for (int j = 0; j < 16; ++j) {
            fx4 v = R[lane + 64 * j];
            s += (v.x + v.y) + (v.z + v.w);
        }
        #pragma unroll
        for (int o = 32; o > 0; o >>= 1) s += __shfl_down(s, o);
        if (lane == 0) out[row] = s;
    }
}

// ---------------- pass 2: message chain (single block, R3-proven) ----------------

__device__ __forceinline__ float block_sum_1024(float v, float* red) {
    #pragma unroll
    for (int o = 32; o > 0; o >>= 1) v += __shfl_down(v, o);
    int lane = threadIdx.x & 63, wid = threadIdx.x >> 6;
    if (lane == 0) red[wid] = v;
    __syncthreads();
    if (threadIdx.x == 0) {
        float t = 0.f;
        #pragma unroll
        for (int w = 0; w < 16; ++w) t += red[w];
        red[0] = t;
    }
    __syncthreads();
    float r = red[0];
    __syncthreads();
    return r;
}

__global__ void __launch_bounds__(1024) messages_kernel(
        const float* __restrict__ ws,
        const int* __restrict__ op0, const int* __restrict__ op1,
        const int* __restrict__ op2, const int* __restrict__ op3,
        float* __restrict__ ws_w) {
    __shared__ float m0[D], m1[D], m2[D], m3[D];
    __shared__ float red[16];
    int tid = threadIdx.x;

    int s0[4], d0[4], s1[4], d1[4], s2[4], d2[4], s3[4], d3[4];
    #pragma unroll
    for (int k = 0; k < 4; ++k) {
        int i = tid + k * 1024;
        s0[k] = op0[i]; d0[k] = op0[D + i];
        s1[k] = op1[i]; d1[k] = op1[D + i];
        s2[k] = op2[i]; d2[k] = op2[D + i];
        s3[k] = op3[i]; d3[k] = op3[D + i];
    }
    float g0[4], g1[4], g2[4], g3[4];
    #pragma unroll
    for (int k = 0; k < 4; ++k) {
        g0[k] = ws[CS0 + s0[k]];
        g1[k] = ws[CS1 + s1[k]];
        g2[k] = ws[RS2 + s2[k]];
        g3[k] = ws[RS1 + s3[k]];
    }

    #pragma unroll
    for (int k = 0; k < 4; ++k) {
        int i = tid + k * 1024;
        m0[i] = 0.f; m1[i] = 0.f; m2[i] = 0.f; m3[i] = 0.f;
    }
    __syncthreads();

    #pragma unroll
    for (int k = 0; k < 4; ++k) atomicAdd(&m0[d0[k]], g0[k]);
    __syncthreads();

    float p = 0.f;
    #pragma unroll
    for (int k = 0; k < 4; ++k) p += m0[tid + k * 1024];
    float S0 = block_sum_1024(p, red);

    #pragma unroll
    for (int k = 0; k < 4; ++k) atomicAdd(&m1[d1[k]], g1[k] + S0);
    __syncthreads();

    #pragma unroll
    for (int k = 0; k < 4; ++k)
        atomicAdd(&m2[d2[k]], g2[k] + 4095.0f * m1[s2[k]]);
    __syncthreads();

    p = 0.f;
    #pragma unroll
    for (int k = 0; k < 4; ++k) p += m2[tid + k * 1024];
    float S2 = block_sum_1024(p, red);

    #pragma unroll
    for (int k = 0; k < 4; ++k)
        atomicAdd(&m3[d3[k]], g3[k] + 4095.0f * m0[s3[k]] + S2);
    __syncthreads();

    #pragma unroll
    for (int k = 0; k < 4; ++k) {
        int i = tid + k * 1024;
        ws_w[MSG + 0 * D + i] = m0[i];
        ws_w[MSG + 1 * D + i] = m1[i];
        ws_w[MSG + 2 * D + i] = m2[i];
        ws_w[MSG + 3 * D + i] = m3[i];
    }
}

// ---------------- pass 3: apply broadcasts ----------------
// 3*D blocks x 256; ONLY change vs R3: mat = 2 - (b>>12)  (t2 applied FIRST,
// while it is still IC-resident from reduce's tail; t0 last).
__global__ void __launch_bounds__(256) apply_kernel(
        const float* __restrict__ t0, const float* __restrict__ t1,
        const float* __restrict__ t2, const float* __restrict__ msgs,
        float* __restrict__ out) {
    int b = blockIdx.x;
    int mat = 2 - (b >> 12);
    int row = b & (D - 1);
    const float* m0 = msgs + 0 * D;
    const float* m1 = msgs + 1 * D;
    const float* m2 = msgs + 2 * D;
    const float* m3 = msgs + 3 * D;
    size_t base = (size_t)row * D;
    fx4* dst = (fx4*)(out + (size_t)mat * D * D + base);

    if (mat == 0) {
        const fx4* src = (const fx4*)(t0 + base);
        const fx4* c4 = (const fx4*)m3;
        for (int i = threadIdx.x; i < D / 4; i += 256) {
            fx4 r = __builtin_nontemporal_load(&src[i]) + c4[i];
            __builtin_nontemporal_store(r, &dst[i]);
        }
    } else if (mat == 1) {
        const fx4* src = (const fx4*)(t1 + base);
        const fx4* c4 = (const fx4*)m2;
        float rr = m0[row];
        for (int i = threadIdx.x; i < D / 4; i += 256) {
            fx4 r = __builtin_nontemporal_load(&src[i]) + c4[i] + rr;
            __builtin_nontemporal_store(r, &dst[i]);
        }
    } else {
        const fx4* src = (const fx4*)(t2 + base);
        float rr = m1[row];
        for (int i = threadIdx.x; i < D / 4; i += 256) {
            fx4 r = __builtin_nontemporal_load(&src[i]) + rr;
            __builtin_nontemporal_store(r, &dst[i]);
        }
    }
}

extern "C" void kernel_launch(void* const* d_in, const int* in_sizes, int n_in,
                              void* d_out, int out_size, void* d_ws, size_t ws_size,
                              hipStream_t stream) {
    const float* t0 = (const float*)d_in[0];
    const float* t1 = (const float*)d_in[1];
    const float* t2 = (const float*)d_in[2];
    const int* op0 = (const int*)d_in[3];
    const int* op1 = (const int*)d_in[4];
    const int* op2 = (const int*)d_in[5];
    const int* op3 = (const int*)d_in[6];
    float* out = (float*)d_out;
    float* ws = (float*)d_ws;

    hipMemsetAsync(ws, 0, 2 * D * sizeof(float), stream);

    reduce_all_kernel<<<2560, 256, 0, stream>>>(t0, t1, t2, ws);
    messages_kernel<<<1, 1024, 0, stream>>>(ws, op0, op1, op2, op3, ws);
    apply_kernel<<<3 * D, 256, 0, stream>>>(t0, t1, t2, ws + MSG, out);
}